// Round 1
// baseline (385.150 us; speedup 1.0000x reference)
//
#include <hip/hip_runtime.h>
#include <math.h>

typedef _Float16 f16;
typedef __attribute__((ext_vector_type(4))) _Float16 f16x4;
typedef __attribute__((ext_vector_type(8))) _Float16 f16x8;
typedef __attribute__((ext_vector_type(4))) float f32x4;

#define NB 2
#define NH 16
#define TQ 1024
#define TK 2048
#define DM 1536
#define HD 96
#define RH 48

__device__ __forceinline__ f32x4 mfma16(f16x8 a, f16x8 b, f32x4 c) {
    return __builtin_amdgcn_mfma_f32_16x16x32_f16(a, b, c, 0, 0, 0);
}

#define GLDS16(gptr, lptr) __builtin_amdgcn_global_load_lds( \
    (const __attribute__((address_space(1))) unsigned int*)(gptr), \
    (__attribute__((address_space(3))) unsigned int*)(lptr), 16, 0, 0)

// ---------------- f32 -> f16 conversion (vectorized) ----------------
__global__ void cvt_k(const float4* __restrict__ in, f16x4* __restrict__ out, int n4) {
    int i = blockIdx.x * 256 + threadIdx.x;
    if (i >= n4) return;
    float4 v = in[i];
    f16x4 o;
    o[0] = (f16)v.x; o[1] = (f16)v.y; o[2] = (f16)v.z; o[3] = (f16)v.w;
    out[i] = o;
}

// ---------------- RoPE sin/cos tables: [B*T][48] ----------------
__global__ void rope_table_k(const float* __restrict__ coords,
                             float* __restrict__ sinT, float* __restrict__ cosT, int n) {
    int i = blockIdx.x * 256 + threadIdx.x;
    if (i >= n) return;
    int bt = i / 48, idx = i - bt * 48;
    int axis = idx >> 4, f = idx & 15;
    float inv = powf(10000.f, -(float)f * (1.f / 16.f));
    float ang = coords[bt * 3 + axis] * inv;
    sinT[i] = sinf(ang);
    cosT[i] = cosf(ang);
}

// ---------------- RoPE rotation in-place on [B,H,T,96] f16 ----------------
__global__ void rope_apply_k(f16* __restrict__ qk, const float* __restrict__ sinT,
                             const float* __restrict__ cosT, int T, float scale, int n) {
    int i = blockIdx.x * 256 + threadIdx.x;
    if (i >= n) return;
    int p = i % 48;
    int rest = i / 48;              // (b*NH + h)*T + t
    int t = rest % T;
    int b = rest / (NH * T);
    long base = (long)rest * HD;
    float x1 = (float)qk[base + p];
    float x2 = (float)qk[base + p + RH];
    int ti = (b * T + t) * 48 + p;
    float s = sinT[ti], c = cosT[ti];
    qk[base + p]      = (f16)((x1 * c - x2 * s) * scale);
    qk[base + p + RH] = (f16)((x2 * c + x1 * s) * scale);
}

// ---------------- GEMM: C[m,n] = sum_k A[m,k] * W[n,k] + bias[n] ----------------
// MODE 0: write f16 to [B,H,T,96] layout (T tokens per batch). MODE 1: f32 row-major MxN.
template <int MODE>
__global__ __launch_bounds__(256) void gemm16(
    const f16* __restrict__ A, const f16* __restrict__ W,
    const float* __restrict__ bias, void* __restrict__ outp,
    int M, int N, int K, int T) {
    __shared__ f16 Als[128 * 32];
    __shared__ f16 Bls[128 * 32];
    const int tid = threadIdx.x;
    const int w = tid >> 6, lane = tid & 63;
    const int m0 = blockIdx.y * 128, n0 = blockIdx.x * 128;
    const int wm = (w & 1) * 64, wn = (w >> 1) * 64;
    f32x4 acc[4][4] = {};
    const int srow = lane >> 2, scol = (lane & 3) * 8;
    const long arow0 = (long)(m0 + 32 * w + srow);
    const long brow0 = (long)(n0 + 32 * w + srow);

    for (int k0 = 0; k0 < K; k0 += 32) {
        __syncthreads();   // protect previous iteration's fragment reads
        GLDS16(A + arow0 * K + k0 + scol,        &Als[(32 * w) * 32]);
        GLDS16(A + (arow0 + 16) * K + k0 + scol, &Als[(32 * w + 16) * 32]);
        GLDS16(W + brow0 * K + k0 + scol,        &Bls[(32 * w) * 32]);
        GLDS16(W + (brow0 + 16) * K + k0 + scol, &Bls[(32 * w + 16) * 32]);
        __syncthreads();   // implies vmcnt drain of global_load_lds

        f16x8 af[4], bf[4];
#pragma unroll
        for (int i = 0; i < 4; i++) {
            af[i] = *(const f16x8*)&Als[(wm + i * 16 + (lane & 15)) * 32 + (lane >> 4) * 8];
            bf[i] = *(const f16x8*)&Bls[(wn + i * 16 + (lane & 15)) * 32 + (lane >> 4) * 8];
        }
#pragma unroll
        for (int i = 0; i < 4; i++)
#pragma unroll
            for (int j = 0; j < 4; j++)
                acc[i][j] = mfma16(af[i], bf[j], acc[i][j]);
    }

#pragma unroll
    for (int i = 0; i < 4; i++) {
#pragma unroll
        for (int j = 0; j < 4; j++) {
#pragma unroll
            for (int r = 0; r < 4; r++) {
                int m = m0 + wm + i * 16 + (lane >> 4) * 4 + r;
                int n = n0 + wn + j * 16 + (lane & 15);
                float v = acc[i][j][r] + bias[n];
                if (MODE == 0) {
                    int b = m / T, t = m - b * T;
                    int h = n / HD, hd = n - h * HD;
                    ((f16*)outp)[(((long)b * NH + h) * T + t) * HD + hd] = (f16)v;
                } else {
                    ((float*)outp)[(long)m * N + n] = v;
                }
            }
        }
    }
}

// ---------------- Flash attention: Q[B,H,TQ,96] x K,V[B,H,TK,96] -> O[B*TQ,1536] f16 ----
// 4 waves/block, each wave owns 16 q-rows. 32-key chunks. exp2 domain (log2e folded into Q).
__global__ __launch_bounds__(256) void attn_fwd(
    const f16* __restrict__ Q, const f16* __restrict__ Kg,
    const f16* __restrict__ Vg, f16* __restrict__ O) {
    __shared__ f16 Kl[32][104];      // [key][hd], +8 pad
    __shared__ f16 Vt[96][40];       // [hd][key], +8 pad (transposed V)
    __shared__ f16 Pl[4][16][40];    // per-wave P tile [q][key]
    const int tid = threadIdx.x, w = tid >> 6, lane = tid & 63;
    const int b = blockIdx.z, h = blockIdx.y, q0 = blockIdx.x * 64;
    const long kvbase = ((long)(b * NH + h)) * TK * HD;
    const long qbase  = ((long)(b * NH + h)) * TQ * HD;

    f16x8 qf[3];
    {
        const int qr = q0 + w * 16 + (lane & 15);
#pragma unroll
        for (int s = 0; s < 3; s++)
            qf[s] = *(const f16x8*)&Q[qbase + (long)qr * HD + (lane >> 4) * 8 + 32 * s];
    }
    float m[4], lsum[4];
#pragma unroll
    for (int j = 0; j < 4; j++) { m[j] = -1e30f; lsum[j] = 0.f; }
    f32x4 acc[6] = {};

    for (int k0 = 0; k0 < TK; k0 += 32) {
        __syncthreads();
        // stage K (row-major) and V (transposed) for this 32-key chunk
        for (int g = tid; g < 384; g += 256) {
            int key = g / 12, seg = g - key * 12;
            const f16x8 kv = *(const f16x8*)&Kg[kvbase + (long)(k0 + key) * HD + seg * 8];
            *(f16x8*)&Kl[key][seg * 8] = kv;
            const f16x8 vv = *(const f16x8*)&Vg[kvbase + (long)(k0 + key) * HD + seg * 8];
#pragma unroll
            for (int j = 0; j < 8; j++) Vt[seg * 8 + j][key] = vv[j];
        }
        __syncthreads();

        // scores: S(16q x 32k), two 16x16 tiles
        f32x4 s0 = {}, s1 = {};
#pragma unroll
        for (int s = 0; s < 3; s++) {
            f16x8 b0 = *(const f16x8*)&Kl[lane & 15][(lane >> 4) * 8 + 32 * s];
            f16x8 b1 = *(const f16x8*)&Kl[(lane & 15) + 16][(lane >> 4) * 8 + 32 * s];
            s0 = mfma16(qf[s], b0, s0);
            s1 = mfma16(qf[s], b1, s1);
        }

        // online softmax (scores already in log2 domain)
        float p0[4], p1[4], corr[4];
#pragma unroll
        for (int j = 0; j < 4; j++) {
            float cm = fmaxf(s0[j], s1[j]);
#pragma unroll
            for (int o = 8; o > 0; o >>= 1) cm = fmaxf(cm, __shfl_xor(cm, o));
            float mn = fmaxf(m[j], cm);
            corr[j] = exp2f(m[j] - mn);
            p0[j] = exp2f(s0[j] - mn);
            p1[j] = exp2f(s1[j] - mn);
            float rs = p0[j] + p1[j];
#pragma unroll
            for (int o = 8; o > 0; o >>= 1) rs += __shfl_xor(rs, o);
            lsum[j] = lsum[j] * corr[j] + rs;
            m[j] = mn;
        }
#pragma unroll
        for (int t = 0; t < 6; t++)
#pragma unroll
            for (int j = 0; j < 4; j++) acc[t][j] *= corr[j];

        // P -> LDS (C/D layout) -> A-fragment layout
#pragma unroll
        for (int j = 0; j < 4; j++) {
            Pl[w][(lane >> 4) * 4 + j][lane & 15] = (f16)p0[j];
            Pl[w][(lane >> 4) * 4 + j][(lane & 15) + 16] = (f16)p1[j];
        }
        f16x8 ap = *(const f16x8*)&Pl[w][lane & 15][(lane >> 4) * 8];
#pragma unroll
        for (int t = 0; t < 6; t++) {
            f16x8 bv = *(const f16x8*)&Vt[t * 16 + (lane & 15)][(lane >> 4) * 8];
            acc[t] = mfma16(ap, bv, acc[t]);
        }
    }

#pragma unroll
    for (int j = 0; j < 4; j++) lsum[j] = 1.0f / lsum[j];
    const long obase = ((long)(b * TQ) + q0 + w * 16) * DM + h * HD;
#pragma unroll
    for (int t = 0; t < 6; t++)
#pragma unroll
        for (int j = 0; j < 4; j++) {
            int row = (lane >> 4) * 4 + j;
            O[obase + (long)row * DM + t * 16 + (lane & 15)] = (f16)(acc[t][j] * lsum[j]);
        }
}

// ---------------- host ----------------
extern "C" void kernel_launch(void* const* d_in, const int* in_sizes, int n_in,
                              void* d_out, int out_size, void* d_ws, size_t ws_size,
                              hipStream_t stream) {
    const float* x   = (const float*)d_in[0];
    const float* mem = (const float*)d_in[1];
    const float* qc  = (const float*)d_in[2];
    const float* mc  = (const float*)d_in[3];
    const float* Wq  = (const float*)d_in[4];
    const float* bq  = (const float*)d_in[5];
    const float* Wk  = (const float*)d_in[6];
    const float* bk  = (const float*)d_in[7];
    const float* Wv  = (const float*)d_in[8];
    const float* bv  = (const float*)d_in[9];
    const float* Wo  = (const float*)d_in[10];
    const float* bo  = (const float*)d_in[11];
    float* out = (float*)d_out;

    const long nx = (long)NB * TQ * DM;      // 3,145,728
    const long nm = (long)NB * TK * DM;      // 6,291,456
    const long nw = (long)DM * DM;           // 2,359,296
    const long nq = (long)NB * NH * TQ * HD; // 3,145,728
    const long nk = (long)NB * NH * TK * HD; // 6,291,456

    char* ws = (char*)d_ws;
    size_t off = 0;
    auto alloc = [&](size_t bytes) { size_t o = off; off = (off + bytes + 255) & ~(size_t)255; return o; };
    f16* x16   = (f16*)(ws + alloc(nx * 2));
    f16* mem16 = (f16*)(ws + alloc(nm * 2));
    f16* wq16  = (f16*)(ws + alloc(nw * 2));
    f16* wk16  = (f16*)(ws + alloc(nw * 2));
    f16* wv16  = (f16*)(ws + alloc(nw * 2));
    f16* wo16  = (f16*)(ws + alloc(nw * 2));
    f16* q16   = (f16*)(ws + alloc(nq * 2));
    f16* k16   = (f16*)(ws + alloc(nk * 2));
    f16* v16   = (f16*)(ws + alloc(nk * 2));
    f16* at16  = (f16*)(ws + alloc(nx * 2));
    float* sinq = (float*)(ws + alloc((size_t)NB * TQ * 48 * 4));
    float* cosq = (float*)(ws + alloc((size_t)NB * TQ * 48 * 4));
    float* sink = (float*)(ws + alloc((size_t)NB * TK * 48 * 4));
    float* cosk = (float*)(ws + alloc((size_t)NB * TK * 48 * 4));

    auto blocks = [](long n) { return (int)((n + 255) / 256); };

    // conversions
    cvt_k<<<blocks(nx / 4), 256, 0, stream>>>((const float4*)x, (f16x4*)x16, (int)(nx / 4));
    cvt_k<<<blocks(nm / 4), 256, 0, stream>>>((const float4*)mem, (f16x4*)mem16, (int)(nm / 4));
    cvt_k<<<blocks(nw / 4), 256, 0, stream>>>((const float4*)Wq, (f16x4*)wq16, (int)(nw / 4));
    cvt_k<<<blocks(nw / 4), 256, 0, stream>>>((const float4*)Wk, (f16x4*)wk16, (int)(nw / 4));
    cvt_k<<<blocks(nw / 4), 256, 0, stream>>>((const float4*)Wv, (f16x4*)wv16, (int)(nw / 4));
    cvt_k<<<blocks(nw / 4), 256, 0, stream>>>((const float4*)Wo, (f16x4*)wo16, (int)(nw / 4));

    // rope tables
    rope_table_k<<<blocks((long)NB * TQ * 48), 256, 0, stream>>>(qc, sinq, cosq, NB * TQ * 48);
    rope_table_k<<<blocks((long)NB * TK * 48), 256, 0, stream>>>(mc, sink, cosk, NB * TK * 48);

    // projections (f16 MFMA)
    gemm16<0><<<dim3(12, 16), 256, 0, stream>>>(x16, wq16, bq, q16, NB * TQ, DM, DM, TQ);
    gemm16<0><<<dim3(12, 32), 256, 0, stream>>>(mem16, wk16, bk, k16, NB * TK, DM, DM, TK);
    gemm16<0><<<dim3(12, 32), 256, 0, stream>>>(mem16, wv16, bv, v16, NB * TK, DM, DM, TK);

    // rope: q gets (1/sqrt(96))*log2(e) folded in, k unscaled
    const float qscale = 0.10206207261596577f * 1.4426950408889634f;
    rope_apply_k<<<blocks((long)NB * NH * TQ * 48), 256, 0, stream>>>(q16, sinq, cosq, TQ, qscale, NB * NH * TQ * 48);
    rope_apply_k<<<blocks((long)NB * NH * TK * 48), 256, 0, stream>>>(k16, sink, cosk, TK, 1.0f, NB * NH * TK * 48);

    // attention
    attn_fwd<<<dim3(TQ / 64, NH, NB), 256, 0, stream>>>(q16, k16, v16, at16);

    // output projection -> f32
    gemm16<1><<<dim3(12, 16), 256, 0, stream>>>(at16, wo16, bo, out, NB * TQ, DM, DM, TQ);
}

// Round 2
// 317.181 us; speedup vs baseline: 1.2143x; 1.2143x over previous
//
#include <hip/hip_runtime.h>
#include <math.h>

typedef _Float16 f16;
typedef __attribute__((ext_vector_type(4))) _Float16 f16x4;
typedef __attribute__((ext_vector_type(8))) _Float16 f16x8;
typedef __attribute__((ext_vector_type(4))) float f32x4;

#define NB 2
#define NH 16
#define TQ 1024
#define TK 2048
#define DM 1536
#define HD 96
#define RH 48
#define KC 64          // keys per attention chunk
#define NCH (TK / KC)  // 32 chunks

__device__ __forceinline__ f32x4 mfma16(f16x8 a, f16x8 b, f32x4 c) {
    return __builtin_amdgcn_mfma_f32_16x16x32_f16(a, b, c, 0, 0, 0);
}

#define GLDS16(gptr, lptr) __builtin_amdgcn_global_load_lds( \
    (const __attribute__((address_space(1))) unsigned int*)(gptr), \
    (__attribute__((address_space(3))) unsigned int*)(lptr), 16, 0, 0)

// ---------------- f32 -> f16 conversion ----------------
__global__ void cvt_k(const float4* __restrict__ in, f16x4* __restrict__ out, int n4) {
    int i = blockIdx.x * 256 + threadIdx.x;
    if (i >= n4) return;
    float4 v = in[i];
    f16x4 o;
    o[0] = (f16)v.x; o[1] = (f16)v.y; o[2] = (f16)v.z; o[3] = (f16)v.w;
    out[i] = o;
}

// ---------------- RoPE sin/cos tables: [B*T][48] ----------------
__global__ void rope_table_k(const float* __restrict__ coords,
                             float* __restrict__ sinT, float* __restrict__ cosT, int n) {
    int i = blockIdx.x * 256 + threadIdx.x;
    if (i >= n) return;
    int bt = i / 48, idx = i - bt * 48;
    int axis = idx >> 4, f = idx & 15;
    float inv = powf(10000.f, -(float)f * (1.f / 16.f));
    float ang = coords[bt * 3 + axis] * inv;
    sinT[i] = sinf(ang);
    cosT[i] = cosf(ang);
}

// ---------------- RoPE rotation in-place on padded [B,H,T,128] f16 ----------------
__global__ void rope_apply_k(f16* __restrict__ qk, const float* __restrict__ sinT,
                             const float* __restrict__ cosT, int T, float scale, int n) {
    int i = blockIdx.x * 256 + threadIdx.x;
    if (i >= n) return;
    int p = i % 48;
    int rest = i / 48;              // (b*NH + h)*T + t
    int t = rest % T;
    int b = rest / (NH * T);
    long base = (long)rest * 128;
    float x1 = (float)qk[base + p];
    float x2 = (float)qk[base + p + RH];
    int ti = (b * T + t) * 48 + p;
    float s = sinT[ti], c = cosT[ti];
    qk[base + p]      = (f16)((x1 * c - x2 * s) * scale);
    qk[base + p + RH] = (f16)((x2 * c + x1 * s) * scale);
}

// ---------------- GEMM: C[m,n] = sum_k A[m,k] * W[n,k] + bias[n] ----------------
// MODE 1: f32 row-major MxN. MODE 2: f16 padded [B,H,T,128]. MODE 3: f16 V^T [B,H,96,TK].
template <int MODE>
__global__ __launch_bounds__(256) void gemm16(
    const f16* __restrict__ A, const f16* __restrict__ W,
    const float* __restrict__ bias, void* __restrict__ outp,
    int M, int N, int K, int T) {
    __shared__ f16 Als[128 * 32];
    __shared__ f16 Bls[128 * 32];
    const int tid = threadIdx.x;
    const int w = tid >> 6, lane = tid & 63;
    const int m0 = blockIdx.y * 128, n0 = blockIdx.x * 128;
    const int wm = (w & 1) * 64, wn = (w >> 1) * 64;
    f32x4 acc[4][4] = {};
    const int srow = lane >> 2, scol = (lane & 3) * 8;
    const long arow0 = (long)(m0 + 32 * w + srow);
    const long brow0 = (long)(n0 + 32 * w + srow);

    for (int k0 = 0; k0 < K; k0 += 32) {
        __syncthreads();
        GLDS16(A + arow0 * K + k0 + scol,        &Als[(32 * w) * 32]);
        GLDS16(A + (arow0 + 16) * K + k0 + scol, &Als[(32 * w + 16) * 32]);
        GLDS16(W + brow0 * K + k0 + scol,        &Bls[(32 * w) * 32]);
        GLDS16(W + (brow0 + 16) * K + k0 + scol, &Bls[(32 * w + 16) * 32]);
        __syncthreads();

        f16x8 af[4], bf[4];
#pragma unroll
        for (int i = 0; i < 4; i++) {
            af[i] = *(const f16x8*)&Als[(wm + i * 16 + (lane & 15)) * 32 + (lane >> 4) * 8];
            bf[i] = *(const f16x8*)&Bls[(wn + i * 16 + (lane & 15)) * 32 + (lane >> 4) * 8];
        }
#pragma unroll
        for (int i = 0; i < 4; i++)
#pragma unroll
            for (int j = 0; j < 4; j++)
                acc[i][j] = mfma16(af[i], bf[j], acc[i][j]);
    }

#pragma unroll
    for (int i = 0; i < 4; i++) {
#pragma unroll
        for (int j = 0; j < 4; j++) {
            const int n = n0 + wn + j * 16 + (lane & 15);
            const int mb = m0 + wm + i * 16 + (lane >> 4) * 4;
            if (MODE == 3) {
                int b = mb / T, t = mb - b * T;
                int h = n / HD, hd = n - h * HD;
                f16x4 pk;
#pragma unroll
                for (int r = 0; r < 4; r++) pk[r] = (f16)(acc[i][j][r] + bias[n]);
                *(f16x4*)&((f16*)outp)[(((long)b * NH + h) * HD + hd) * TK + t] = pk;
            } else {
#pragma unroll
                for (int r = 0; r < 4; r++) {
                    int m = mb + r;
                    float v = acc[i][j][r] + bias[n];
                    if (MODE == 2) {
                        int b = m / T, t = m - b * T;
                        int h = n / HD, hd = n - h * HD;
                        ((f16*)outp)[(((long)b * NH + h) * T + t) * 128 + hd] = (f16)v;
                    } else {
                        ((float*)outp)[(long)m * N + n] = v;
                    }
                }
            }
        }
    }
}

// ---------------- Flash attention ----------------
// Q padded [B,H,TQ,128]; K padded [B,H,TK,128]; V^T [B,H,96,TK]; O = at16 [B*TQ,1536] f16.
// 4 waves/block, 32 q-rows/wave (2 q-tiles), 64-key chunks, full LDS double-buffer,
// one barrier per chunk. All LDS tiles XOR-swizzled (seg ^= row&7) with pre-swizzled
// global source addresses (global_load_lds writes linearly).
__global__ __launch_bounds__(256, 1) void attn_fwd(
    const f16* __restrict__ Q, const f16* __restrict__ Kg,
    const f16* __restrict__ Vg, f16* __restrict__ O) {
    __shared__ f16 Kl[2][64 * 128];   // rows 256B (16 segs of 16B), swizzled
    __shared__ f16 Vl[2][96 * 64];    // rows 128B (8 segs), swizzled
    __shared__ f16 Pl[4][16 * 64];    // per-wave, rows 128B (8 segs), swizzled

    const int tid = threadIdx.x, w = tid >> 6, lane = tid & 63;
    const int l15 = lane & 15, g = lane >> 4;

    // bijective XCD swizzle: co-locate the 8 q-chunks of each head on one XCD
    const int linear = blockIdx.x + (int)(gridDim.x * (blockIdx.y + gridDim.y * blockIdx.z));
    const int wid = (linear & 7) * 32 + (linear >> 3);
    const int qc = wid & 7, h = (wid >> 3) & 15, b = wid >> 7;

    const long kbase = ((long)(b * NH + h)) * TK * 128;
    const long vbase = ((long)(b * NH + h)) * HD * TK;
    const long qbase = ((long)(b * NH + h)) * TQ * 128;
    const int q0 = qc * 128 + w * 32;

    // per-lane pre-swizzled staging source offsets (f16 units, within one chunk)
    int ksrc[4], vsrc[3];
#pragma unroll
    for (int i = 0; i < 4; i++) {
        int Lb = w * 4096 + i * 1024 + lane * 16;     // linear LDS byte offset
        int r = Lb >> 8, s = (Lb >> 4) & 15;
        ksrc[i] = r * 128 + ((s ^ (r & 7)) * 8);
    }
#pragma unroll
    for (int i = 0; i < 3; i++) {
        int Lb = w * 3072 + i * 1024 + lane * 16;
        int r = Lb >> 7, s = (Lb >> 4) & 7;
        vsrc[i] = r * TK + ((s ^ (r & 7)) * 8);
    }

    // Q fragments (2 q-tiles x 3 k-steps; pad k-step skipped)
    f16x8 qf[2][3];
#pragma unroll
    for (int qt = 0; qt < 2; qt++)
#pragma unroll
        for (int s = 0; s < 3; s++)
            qf[qt][s] = *(const f16x8*)&Q[qbase + (long)(q0 + qt * 16 + l15) * 128 + g * 8 + 32 * s];

    float mx[2][4], ls[2][4];
#pragma unroll
    for (int qt = 0; qt < 2; qt++)
#pragma unroll
        for (int j = 0; j < 4; j++) { mx[qt][j] = -1e30f; ls[qt][j] = 0.f; }
    f32x4 acc[2][6] = {};

#define STAGE(buf, c) do { \
    const f16* kp_ = Kg + kbase + (long)(c) * (KC * 128); \
    _Pragma("unroll") for (int i_ = 0; i_ < 4; i_++) \
        GLDS16(kp_ + ksrc[i_], &Kl[buf][w * 2048 + i_ * 512]); \
    const f16* vp_ = Vg + vbase + (c) * KC; \
    _Pragma("unroll") for (int i_ = 0; i_ < 3; i_++) \
        GLDS16(vp_ + vsrc[i_], &Vl[buf][w * 1536 + i_ * 512]); \
} while (0)

    STAGE(0, 0);

    for (int c = 0; c < NCH; ++c) {
        __syncthreads();                 // drains GLDS of chunk c; guards buffer reuse
        const int buf = c & 1;
        if (c + 1 < NCH) STAGE(buf ^ 1, c + 1);

        // ---- QK^T: 8 score tiles (2 qt x 4 kt), K=96 in 3 steps ----
        f32x4 sa[2][4] = {};
#pragma unroll
        for (int kt = 0; kt < 4; kt++)
#pragma unroll
            for (int s = 0; s < 3; s++) {
                int r = kt * 16 + l15;
                int seg = g + 4 * s;
                f16x8 kf = *(const f16x8*)&Kl[buf][r * 128 + ((seg ^ (r & 7)) * 8)];
                sa[0][kt] = mfma16(qf[0][s], kf, sa[0][kt]);
                sa[1][kt] = mfma16(qf[1][s], kf, sa[1][kt]);
            }

        // ---- online softmax (log2 domain; scale folded into Q) ----
#pragma unroll
        for (int qt = 0; qt < 2; qt++) {
            float corr[4];
#pragma unroll
            for (int j = 0; j < 4; j++) {
                float cm = fmaxf(fmaxf(sa[qt][0][j], sa[qt][1][j]),
                                 fmaxf(sa[qt][2][j], sa[qt][3][j]));
#pragma unroll
                for (int o = 8; o > 0; o >>= 1) cm = fmaxf(cm, __shfl_xor(cm, o));
                float mn = fmaxf(mx[qt][j], cm);
                corr[j] = exp2f(mx[qt][j] - mn);
                mx[qt][j] = mn;
                float rs = 0.f;
#pragma unroll
                for (int kt = 0; kt < 4; kt++) {
                    sa[qt][kt][j] = exp2f(sa[qt][kt][j] - mn);
                    rs += sa[qt][kt][j];
                }
#pragma unroll
                for (int o = 8; o > 0; o >>= 1) rs += __shfl_xor(rs, o);
                ls[qt][j] = ls[qt][j] * corr[j] + rs;
            }
#pragma unroll
            for (int t = 0; t < 6; t++)
#pragma unroll
                for (int j = 0; j < 4; j++) acc[qt][t][j] *= corr[j];
        }

        // ---- P -> per-wave LDS (swizzled) -> A-fragments ----
        f16x8 ap[2][2];
#pragma unroll
        for (int qt = 0; qt < 2; qt++) {
#pragma unroll
            for (int kt = 0; kt < 4; kt++)
#pragma unroll
                for (int j = 0; j < 4; j++) {
                    int qr = g * 4 + j;
                    int col = kt * 16 + l15;
                    int seg = col >> 3;
                    Pl[w][qr * 64 + ((seg ^ (qr & 7)) * 8) + (col & 7)] = (f16)sa[qt][kt][j];
                }
#pragma unroll
            for (int ks = 0; ks < 2; ks++) {
                int seg = g + 4 * ks;
                ap[qt][ks] = *(const f16x8*)&Pl[w][l15 * 64 + ((seg ^ (l15 & 7)) * 8)];
            }
        }

        // ---- PV: O += P * V (V^T rows, keys contiguous) ----
#pragma unroll
        for (int ks = 0; ks < 2; ks++)
#pragma unroll
            for (int t = 0; t < 6; t++) {
                int r = t * 16 + l15;
                int seg = g + 4 * ks;
                f16x8 vf = *(const f16x8*)&Vl[buf][r * 64 + ((seg ^ (r & 7)) * 8)];
                acc[0][t] = mfma16(ap[0][ks], vf, acc[0][t]);
                acc[1][t] = mfma16(ap[1][ks], vf, acc[1][t]);
            }
    }

    // ---- epilogue ----
    float inv[2][4];
#pragma unroll
    for (int qt = 0; qt < 2; qt++)
#pragma unroll
        for (int j = 0; j < 4; j++) inv[qt][j] = 1.0f / ls[qt][j];
    const long ob = ((long)b * TQ + q0) * DM + h * HD;
#pragma unroll
    for (int qt = 0; qt < 2; qt++)
#pragma unroll
        for (int t = 0; t < 6; t++)
#pragma unroll
            for (int j = 0; j < 4; j++) {
                int row = qt * 16 + g * 4 + j;
                O[ob + (long)row * DM + t * 16 + l15] = (f16)(acc[qt][t][j] * inv[qt][j]);
            }
}

// ---------------- host ----------------
extern "C" void kernel_launch(void* const* d_in, const int* in_sizes, int n_in,
                              void* d_out, int out_size, void* d_ws, size_t ws_size,
                              hipStream_t stream) {
    const float* x   = (const float*)d_in[0];
    const float* mem = (const float*)d_in[1];
    const float* qc  = (const float*)d_in[2];
    const float* mc  = (const float*)d_in[3];
    const float* Wq  = (const float*)d_in[4];
    const float* bq  = (const float*)d_in[5];
    const float* Wk  = (const float*)d_in[6];
    const float* bk  = (const float*)d_in[7];
    const float* Wv  = (const float*)d_in[8];
    const float* bv  = (const float*)d_in[9];
    const float* Wo  = (const float*)d_in[10];
    const float* bo  = (const float*)d_in[11];
    float* out = (float*)d_out;

    const long nx = (long)NB * TQ * DM;
    const long nm = (long)NB * TK * DM;
    const long nw = (long)DM * DM;
    const long nqp = (long)NB * NH * TQ * 128;   // padded Q
    const long nkp = (long)NB * NH * TK * 128;   // padded K
    const long nvt = (long)NB * NH * HD * TK;    // V^T

    char* ws = (char*)d_ws;
    size_t off = 0;
    auto alloc = [&](size_t bytes) { size_t o = off; off = (off + bytes + 255) & ~(size_t)255; return o; };
    f16* x16   = (f16*)(ws + alloc(nx * 2));     // also reused as at16 (attn output)
    f16* mem16 = (f16*)(ws + alloc(nm * 2));
    f16* wq16  = (f16*)(ws + alloc(nw * 2));
    f16* wk16  = (f16*)(ws + alloc(nw * 2));
    f16* wv16  = (f16*)(ws + alloc(nw * 2));
    f16* wo16  = (f16*)(ws + alloc(nw * 2));
    f16* q16p  = (f16*)(ws + alloc(nqp * 2));
    f16* k16p  = (f16*)(ws + alloc(nkp * 2));
    f16* vt16  = (f16*)(ws + alloc(nvt * 2));
    float* sinq = (float*)(ws + alloc((size_t)NB * TQ * 48 * 4));
    float* cosq = (float*)(ws + alloc((size_t)NB * TQ * 48 * 4));
    float* sink = (float*)(ws + alloc((size_t)NB * TK * 48 * 4));
    float* cosk = (float*)(ws + alloc((size_t)NB * TK * 48 * 4));
    f16* at16 = x16;   // alias: x16 dead after Q projection

    auto blocks = [](long n) { return (int)((n + 255) / 256); };

    cvt_k<<<blocks(nx / 4), 256, 0, stream>>>((const float4*)x, (f16x4*)x16, (int)(nx / 4));
    cvt_k<<<blocks(nm / 4), 256, 0, stream>>>((const float4*)mem, (f16x4*)mem16, (int)(nm / 4));
    cvt_k<<<blocks(nw / 4), 256, 0, stream>>>((const float4*)Wq, (f16x4*)wq16, (int)(nw / 4));
    cvt_k<<<blocks(nw / 4), 256, 0, stream>>>((const float4*)Wk, (f16x4*)wk16, (int)(nw / 4));
    cvt_k<<<blocks(nw / 4), 256, 0, stream>>>((const float4*)Wv, (f16x4*)wv16, (int)(nw / 4));
    cvt_k<<<blocks(nw / 4), 256, 0, stream>>>((const float4*)Wo, (f16x4*)wo16, (int)(nw / 4));

    rope_table_k<<<blocks((long)NB * TQ * 48), 256, 0, stream>>>(qc, sinq, cosq, NB * TQ * 48);
    rope_table_k<<<blocks((long)NB * TK * 48), 256, 0, stream>>>(mc, sink, cosk, NB * TK * 48);

    gemm16<2><<<dim3(12, 16), 256, 0, stream>>>(x16, wq16, bq, q16p, NB * TQ, DM, DM, TQ);
    gemm16<2><<<dim3(12, 32), 256, 0, stream>>>(mem16, wk16, bk, k16p, NB * TK, DM, DM, TK);
    gemm16<3><<<dim3(12, 32), 256, 0, stream>>>(mem16, wv16, bv, vt16, NB * TK, DM, DM, TK);

    const float qscale = 0.10206207261596577f * 1.4426950408889634f;  // 1/sqrt(96) * log2(e)
    rope_apply_k<<<blocks((long)NB * NH * TQ * 48), 256, 0, stream>>>(q16p, sinq, cosq, TQ, qscale, NB * NH * TQ * 48);
    rope_apply_k<<<blocks((long)NB * NH * TK * 48), 256, 0, stream>>>(k16p, sink, cosk, TK, 1.0f, NB * NH * TK * 48);

    attn_fwd<<<dim3(TQ / 128, NH, NB), 256, 0, stream>>>(q16p, k16p, vt16, at16);

    gemm16<1><<<dim3(12, 16), 256, 0, stream>>>(at16, wo16, bo, out, NB * TQ, DM, DM, TQ);
}

// Round 3
// 210.385 us; speedup vs baseline: 1.8307x; 1.5076x over previous
//
#include <hip/hip_runtime.h>
#include <math.h>

typedef _Float16 f16;
typedef __attribute__((ext_vector_type(4))) _Float16 f16x4;
typedef __attribute__((ext_vector_type(8))) _Float16 f16x8;
typedef __attribute__((ext_vector_type(4))) float f32x4;
typedef __attribute__((ext_vector_type(16))) float f32x16;

#define NB 2
#define NH 16
#define TQ 1024
#define TK 2048
#define DM 1536
#define HD 96
#define RH 48

__device__ __forceinline__ f32x4 mfma16(f16x8 a, f16x8 b, f32x4 c) {
    return __builtin_amdgcn_mfma_f32_16x16x32_f16(a, b, c, 0, 0, 0);
}

#define GLDS16(gptr, lptr) __builtin_amdgcn_global_load_lds( \
    (const __attribute__((address_space(1))) unsigned int*)(gptr), \
    (__attribute__((address_space(3))) unsigned int*)(lptr), 16, 0, 0)

// ---------------- conversions (fused launches) ----------------
__global__ void cvt_w4(const float4* __restrict__ W0, const float4* __restrict__ W1,
                       const float4* __restrict__ W2, const float4* __restrict__ W3,
                       f16x4* __restrict__ o0, f16x4* __restrict__ o1,
                       f16x4* __restrict__ o2, f16x4* __restrict__ o3, int n4) {
    int i = blockIdx.x * 256 + threadIdx.x;
    if (i >= n4) return;
    const float4* in = blockIdx.y == 0 ? W0 : blockIdx.y == 1 ? W1 : blockIdx.y == 2 ? W2 : W3;
    f16x4* out      = blockIdx.y == 0 ? o0 : blockIdx.y == 1 ? o1 : blockIdx.y == 2 ? o2 : o3;
    float4 v = in[i];
    f16x4 o;
    o[0] = (f16)v.x; o[1] = (f16)v.y; o[2] = (f16)v.z; o[3] = (f16)v.w;
    out[i] = o;
}

__global__ void cvt_xm(const float4* __restrict__ X, const float4* __restrict__ M,
                       f16x4* __restrict__ ox, f16x4* __restrict__ om, int nx4, int nm4) {
    int i = blockIdx.x * 256 + threadIdx.x;
    int n = blockIdx.y == 0 ? nx4 : nm4;
    if (i >= n) return;
    const float4* in = blockIdx.y == 0 ? X : M;
    f16x4* out = blockIdx.y == 0 ? ox : om;
    float4 v = in[i];
    f16x4 o;
    o[0] = (f16)v.x; o[1] = (f16)v.y; o[2] = (f16)v.z; o[3] = (f16)v.w;
    out[i] = o;
}

// ---------------- RoPE sin/cos tables: [B*T][48] ----------------
__global__ void rope_tab2(const float* __restrict__ cq, const float* __restrict__ cm,
                          float* __restrict__ sq, float* __restrict__ cqo,
                          float* __restrict__ sk, float* __restrict__ cko,
                          int nq, int nk) {
    int i = blockIdx.x * 256 + threadIdx.x;
    int n = blockIdx.y == 0 ? nq : nk;
    if (i >= n) return;
    const float* coords = blockIdx.y == 0 ? cq : cm;
    float* sinT = blockIdx.y == 0 ? sq : sk;
    float* cosT = blockIdx.y == 0 ? cqo : cko;
    int bt = i / 48, idx = i - bt * 48;
    int axis = idx >> 4, f = idx & 15;
    float inv = powf(10000.f, -(float)f * (1.f / 16.f));
    float ang = coords[bt * 3 + axis] * inv;
    sinT[i] = sinf(ang);
    cosT[i] = cosf(ang);
}

// ---------------- RoPE rotation in-place on [B,H,T,stride] f16 ----------------
__global__ void rope_apply_k(f16* __restrict__ qk, const float* __restrict__ sinT,
                             const float* __restrict__ cosT, int T, int stride,
                             float scale, int n) {
    int i = blockIdx.x * 256 + threadIdx.x;
    if (i >= n) return;
    int p = i % 48;
    int rest = i / 48;              // (b*NH + h)*T + t
    int t = rest % T;
    int b = rest / (NH * T);
    long base = (long)rest * stride;
    float x1 = (float)qk[base + p];
    float x2 = (float)qk[base + p + RH];
    int ti = (b * T + t) * 48 + p;
    float s = sinT[ti], c = cosT[ti];
    qk[base + p]      = (f16)((x1 * c - x2 * s) * scale);
    qk[base + p + RH] = (f16)((x2 * c + x1 * s) * scale);
}

// ---------------- GEMM: C[m,n] = sum_k A[m,k] * W[n,k] + bias[n] ----------------
// MODE 1: f32 row-major MxN (O-proj).  MODE 2: f16 padded [B,H,T,128] (K-proj).
// MODE 3: f16 V^T [B,H,96,TK].  MODE 4: fused K|V (bx<12 -> MODE2 path, else MODE3).
// MODE 5: f16 unpadded [B,H,T,96] (Q-proj).
template <int MODE, int TM>
__global__ __launch_bounds__(256) void gemm16(
    const f16* __restrict__ A, const f16* __restrict__ Wa, const f16* __restrict__ Wb,
    const float* __restrict__ ba, const float* __restrict__ bb,
    void* __restrict__ outa, void* __restrict__ outb,
    int M, int N, int K, int T) {
    __shared__ f16 Als[TM * 32];
    __shared__ f16 Bls[128 * 32];
    const int tid = threadIdx.x, w = tid >> 6, lane = tid & 63;
    const int l15 = lane & 15, g = lane >> 4;
    int bx = blockIdx.x;
    const f16* W = Wa; const float* bias = ba; void* outp = outa;
    bool sel = false;
    if (MODE == 4 && bx >= 12) { sel = true; W = Wb; bias = bb; outp = outb; bx -= 12; }
    const int m0 = blockIdx.y * TM, n0 = bx * 128;
    const int wm = (TM == 128) ? (w & 1) * 64 : (w & 1) * 32;
    const int wn = (w >> 1) * 64;
    constexpr int MI = (TM == 128) ? 4 : 2;
    f32x4 acc[MI][4] = {};
    const int srow = lane >> 2, scol = (lane & 3) * 8;

    for (int k0 = 0; k0 < K; k0 += 32) {
        __syncthreads();
        if (TM == 128) {
            long ar = (long)(m0 + 32 * w + srow);
            GLDS16(A + ar * K + k0 + scol,        &Als[(32 * w) * 32]);
            GLDS16(A + (ar + 16) * K + k0 + scol, &Als[(32 * w + 16) * 32]);
        } else {
            long ar = (long)(m0 + 16 * w + srow);
            GLDS16(A + ar * K + k0 + scol, &Als[(16 * w) * 32]);
        }
        long br = (long)(n0 + 32 * w + srow);
        GLDS16(W + br * K + k0 + scol,        &Bls[(32 * w) * 32]);
        GLDS16(W + (br + 16) * K + k0 + scol, &Bls[(32 * w + 16) * 32]);
        __syncthreads();

        f16x8 af[MI], bf[4];
#pragma unroll
        for (int i = 0; i < MI; i++)
            af[i] = *(const f16x8*)&Als[(wm + i * 16 + l15) * 32 + g * 8];
#pragma unroll
        for (int j = 0; j < 4; j++)
            bf[j] = *(const f16x8*)&Bls[(wn + j * 16 + l15) * 32 + g * 8];
#pragma unroll
        for (int i = 0; i < MI; i++)
#pragma unroll
            for (int j = 0; j < 4; j++)
                acc[i][j] = mfma16(af[i], bf[j], acc[i][j]);
    }

#pragma unroll
    for (int i = 0; i < MI; i++) {
#pragma unroll
        for (int j = 0; j < 4; j++) {
            const int n = n0 + wn + j * 16 + l15;
            const int mb = m0 + wm + i * 16 + g * 4;
            if (MODE == 3 || (MODE == 4 && sel)) {
                int bq = mb / T, t = mb - bq * T;
                int hh = n / HD, hd = n - hh * HD;
                f16x4 pk;
#pragma unroll
                for (int r = 0; r < 4; r++) pk[r] = (f16)(acc[i][j][r] + bias[n]);
                *(f16x4*)&((f16*)outp)[(((long)bq * NH + hh) * HD + hd) * TK + t] = pk;
            } else if (MODE == 2 || MODE == 4) {
#pragma unroll
                for (int r = 0; r < 4; r++) {
                    int m = mb + r;
                    int bq = m / T, t = m - bq * T;
                    int hh = n / HD, hd = n - hh * HD;
                    ((f16*)outp)[(((long)bq * NH + hh) * T + t) * 128 + hd] = (f16)(acc[i][j][r] + bias[n]);
                }
            } else if (MODE == 5) {
#pragma unroll
                for (int r = 0; r < 4; r++) {
                    int m = mb + r;
                    int bq = m / T, t = m - bq * T;
                    int hh = n / HD, hd = n - hh * HD;
                    ((f16*)outp)[(((long)bq * NH + hh) * T + t) * 96 + hd] = (f16)(acc[i][j][r] + bias[n]);
                }
            } else {
#pragma unroll
                for (int r = 0; r < 4; r++)
                    ((float*)outp)[(long)(mb + r) * N + n] = acc[i][j][r] + bias[n];
            }
        }
    }
}

// ---------------- Flash attention v3 ----------------
// Q [B,H,TQ,96]; K padded [B,H,TK,128]; V^T [B,H,96,TK]; O [B*TQ,1536] f16.
// Grid 512 blocks (64 q-rows each), 4 waves = 2 q-groups x 2 key-halves (split-K).
// 32x32x16 MFMA, swapped QK^T (S^T: lane owns q-col -> in-register softmax),
// PV as O^T = mfma(V, P) (acc col = q, rescale lane-local). Single-buffered
// 64-key chunks per half; split-K merge through LDS at the end.
__global__ __launch_bounds__(256, 2) void attn_fwd(
    const f16* __restrict__ Q, const f16* __restrict__ Kg,
    const f16* __restrict__ Vg, f16* __restrict__ O) {
    __shared__ f16 Kl[2][64 * 128];   // per key-half, rows 256B, seg^(row&7) swizzle
    __shared__ f16 Vl[2][96 * 64];    // per key-half, rows 128B, swizzled
    __shared__ f16 Pl[4][32 * 64];    // per wave,   rows 128B, swizzled

    const int tid = threadIdx.x, w = tid >> 6, lane = tid & 63;
    const int q31 = lane & 31, hf = lane >> 5;
    const int half = w >> 1, u = w & 1;   // key-half, q-group

    // bijective XCD swizzle: 64 consecutive wids (4 heads) per XCD
    const int linear = blockIdx.x + (int)(gridDim.x * (blockIdx.y + gridDim.y * blockIdx.z));
    const int wid = (linear & 7) * 64 + (linear >> 3);
    const int qc = wid & 15, h = (wid >> 4) & 15, b = wid >> 8;

    const long kbase = (long)(b * NH + h) * TK * 128;
    const long vbase = (long)(b * NH + h) * HD * TK;
    const long qbase = (long)(b * NH + h) * TQ * 96;
    const int q0 = qc * 64 + u * 32;

    // per-lane pre-swizzled staging source offsets (f16 units)
    int ksrc[8], vsrc[6];
#pragma unroll
    for (int i = 0; i < 8; i++) {
        int L = (u * 8 + i) * 1024 + lane * 16;   // linear byte offset in 16KB tile
        int r = L >> 8, s = (L >> 4) & 15;
        ksrc[i] = r * 128 + ((s ^ (r & 7)) << 3);
    }
#pragma unroll
    for (int i = 0; i < 6; i++) {
        int L = (u * 6 + i) * 1024 + lane * 16;   // 12KB tile
        int r = L >> 7, s = (L >> 4) & 7;
        vsrc[i] = r * TK + ((s ^ (r & 7)) << 3);
    }

    // Q fragments (B-operand of swapped QK^T): lane holds Q[q=q31][d=hf*8+16s..]
    f16x8 qf[6];
#pragma unroll
    for (int s = 0; s < 6; s++)
        qf[s] = *(const f16x8*)&Q[qbase + (long)(q0 + q31) * 96 + hf * 8 + 16 * s];

    float mx = -3e38f, ls = 0.f;
    f32x16 acc[3] = {};

#define STAGE(c_) do { \
    const f16* kp_ = Kg + kbase + (long)(half * 16 + (c_)) * (64 * 128); \
    _Pragma("unroll") for (int i_ = 0; i_ < 8; i_++) \
        GLDS16(kp_ + ksrc[i_], &Kl[half][(u * 8 + i_) * 512]); \
    const f16* vp_ = Vg + vbase + (half * 16 + (c_)) * 64; \
    _Pragma("unroll") for (int i_ = 0; i_ < 6; i_++) \
        GLDS16(vp_ + vsrc[i_], &Vl[half][(u * 6 + i_) * 512]); \
} while (0)

    STAGE(0);

    for (int c = 0; c < 16; ++c) {
        __syncthreads();   // stage(c) complete (vmcnt drained per-wave before barrier)

        // ---- S^T = K * Q^T : 2 key-tiles of 32x32, K-dim 96 in 6 steps ----
        f32x16 st[2] = {};
#pragma unroll
        for (int kt = 0; kt < 2; kt++)
#pragma unroll
            for (int s = 0; s < 6; s++) {
                f16x8 kf = *(const f16x8*)&Kl[half][(kt * 32 + q31) * 128 +
                                                    (((hf + 2 * s) ^ (q31 & 7)) << 3)];
                st[kt] = __builtin_amdgcn_mfma_f32_32x32x16_f16(kf, qf[s], st[kt], 0, 0, 0);
            }

        // ---- online softmax, lane-local q (log2 domain) ----
        float t16[16];
#pragma unroll
        for (int r = 0; r < 16; r++) t16[r] = fmaxf(st[0][r], st[1][r]);
#pragma unroll
        for (int o = 8; o >= 1; o >>= 1)
#pragma unroll
            for (int r = 0; r < o; r++) t16[r] = fmaxf(t16[r], t16[r + o]);
        float cm = fmaxf(t16[0], __shfl_xor(t16[0], 32));
        float mn = fmaxf(mx, cm);
        float corr = exp2f(mx - mn);
        mx = mn;
#pragma unroll
        for (int kt = 0; kt < 2; kt++)
#pragma unroll
            for (int r = 0; r < 16; r++) st[kt][r] = exp2f(st[kt][r] - mn);
        float s16[16];
#pragma unroll
        for (int r = 0; r < 16; r++) s16[r] = st[0][r] + st[1][r];
#pragma unroll
        for (int o = 8; o >= 1; o >>= 1)
#pragma unroll
            for (int r = 0; r < o; r++) s16[r] += s16[r + o];
        ls = ls * corr + s16[0];
#pragma unroll
        for (int dt = 0; dt < 3; dt++)
#pragma unroll
            for (int r = 0; r < 16; r++) acc[dt][r] *= corr;

        // ---- P -> per-wave LDS (packed f16x4, swizzled) ----
        // reg r of tile kt = key (r&3) + 8*(r>>2) + 4*hf + 32*kt, col q31
#pragma unroll
        for (int kt = 0; kt < 2; kt++)
#pragma unroll
            for (int jq = 0; jq < 4; jq++) {
                f16x4 pk;
#pragma unroll
                for (int e = 0; e < 4; e++) pk[e] = (f16)st[kt][jq * 4 + e];
                int seg = kt * 4 + jq;
                *(f16x4*)&Pl[w][q31 * 64 + ((seg ^ (q31 & 7)) << 3) + hf * 4] = pk;
            }

        // ---- PV: O^T += V * P  (A=V keeps d rows, B=P keeps q cols) ----
#pragma unroll
        for (int ks = 0; ks < 4; ks++) {
            f16x8 pf = *(const f16x8*)&Pl[w][q31 * 64 + (((hf + 2 * ks) ^ (q31 & 7)) << 3)];
#pragma unroll
            for (int dt = 0; dt < 3; dt++) {
                f16x8 vf = *(const f16x8*)&Vl[half][(dt * 32 + q31) * 64 +
                                                    (((hf + 2 * ks) ^ (q31 & 7)) << 3)];
                acc[dt] = __builtin_amdgcn_mfma_f32_32x32x16_f16(vf, pf, acc[dt], 0, 0, 0);
            }
        }

        __syncthreads();   // all reads of chunk c done -> safe to overwrite
        if (c < 15) STAGE(c + 1);
    }

    // ---- split-K merge: halves 1 dump state, halves 0 combine + store ----
    ls += __shfl_xor(ls, 32);
    float* dump = (float*)&Kl[0][0] + u * (64 * 52);
    __syncthreads();
    if (half == 1) {
        float* dl = dump + lane * 52;
        dl[0] = mx; dl[1] = ls;
#pragma unroll
        for (int dt = 0; dt < 3; dt++)
#pragma unroll
            for (int r = 0; r < 16; r++) dl[2 + dt * 16 + r] = acc[dt][r];
    }
    __syncthreads();
    if (half == 0) {
        const float* dl = dump + lane * 52;
        float mb = dl[0], lsb = dl[1];
        float mf = fmaxf(mx, mb);
        float ca = exp2f(mx - mf), cb = exp2f(mb - mf);
        float inv = 1.f / (ls * ca + lsb * cb);
        const long orow = (long)(b * TQ + q0 + q31) * DM + h * 96;
#pragma unroll
        for (int dt = 0; dt < 3; dt++)
#pragma unroll
            for (int jq = 0; jq < 4; jq++) {
                f16x4 ov;
#pragma unroll
                for (int e = 0; e < 4; e++) {
                    int r = jq * 4 + e;
                    ov[e] = (f16)((acc[dt][r] * ca + dl[2 + dt * 16 + r] * cb) * inv);
                }
                *(f16x4*)&O[orow + dt * 32 + jq * 8 + hf * 4] = ov;
            }
    }
}

// ---------------- host ----------------
extern "C" void kernel_launch(void* const* d_in, const int* in_sizes, int n_in,
                              void* d_out, int out_size, void* d_ws, size_t ws_size,
                              hipStream_t stream) {
    const float* x   = (const float*)d_in[0];
    const float* mem = (const float*)d_in[1];
    const float* qc  = (const float*)d_in[2];
    const float* mc  = (const float*)d_in[3];
    const float* Wq  = (const float*)d_in[4];
    const float* bq  = (const float*)d_in[5];
    const float* Wk  = (const float*)d_in[6];
    const float* bk  = (const float*)d_in[7];
    const float* Wv  = (const float*)d_in[8];
    const float* bv  = (const float*)d_in[9];
    const float* Wo  = (const float*)d_in[10];
    const float* bo  = (const float*)d_in[11];
    float* out = (float*)d_out;

    const long nx  = (long)NB * TQ * DM;
    const long nm  = (long)NB * TK * DM;
    const long nw  = (long)DM * DM;
    const long nq  = (long)NB * NH * TQ * 96;    // unpadded Q
    const long nkp = (long)NB * NH * TK * 128;   // padded K
    const long nvt = (long)NB * NH * HD * TK;    // V^T

    char* ws = (char*)d_ws;
    size_t off = 0;
    auto alloc = [&](size_t bytes) { size_t o = off; off = (off + bytes + 255) & ~(size_t)255; return o; };
    f16* x16   = (f16*)(ws + alloc(nx * 2));     // reused as at16 after Q-proj
    f16* mem16 = (f16*)(ws + alloc(nm * 2));
    f16* wq16  = (f16*)(ws + alloc(nw * 2));
    f16* wk16  = (f16*)(ws + alloc(nw * 2));
    f16* wv16  = (f16*)(ws + alloc(nw * 2));
    f16* wo16  = (f16*)(ws + alloc(nw * 2));
    f16* q16   = (f16*)(ws + alloc(nq * 2));
    f16* k16p  = (f16*)(ws + alloc(nkp * 2));
    f16* vt16  = (f16*)(ws + alloc(nvt * 2));
    float* sinq = (float*)(ws + alloc((size_t)NB * TQ * 48 * 4));
    float* cosq = (float*)(ws + alloc((size_t)NB * TQ * 48 * 4));
    float* sink = (float*)(ws + alloc((size_t)NB * TK * 48 * 4));
    float* cosk = (float*)(ws + alloc((size_t)NB * TK * 48 * 4));
    f16* at16 = x16;

    // conversions: 2 launches
    cvt_w4<<<dim3((int)(nw / 4 / 256), 4), 256, 0, stream>>>(
        (const float4*)Wq, (const float4*)Wk, (const float4*)Wv, (const float4*)Wo,
        (f16x4*)wq16, (f16x4*)wk16, (f16x4*)wv16, (f16x4*)wo16, (int)(nw / 4));
    cvt_xm<<<dim3((int)(nm / 4 / 256), 2), 256, 0, stream>>>(
        (const float4*)x, (const float4*)mem, (f16x4*)x16, (f16x4*)mem16,
        (int)(nx / 4), (int)(nm / 4));

    // rope tables: 1 launch
    rope_tab2<<<dim3((NB * TK * 48 + 255) / 256, 2), 256, 0, stream>>>(
        qc, mc, sinq, cosq, sink, cosk, NB * TQ * 48, NB * TK * 48);

    // projections
    gemm16<5, 64><<<dim3(12, 32), 256, 0, stream>>>(
        x16, wq16, nullptr, bq, nullptr, q16, nullptr, NB * TQ, DM, DM, TQ);
    gemm16<4, 128><<<dim3(24, 32), 256, 0, stream>>>(
        mem16, wk16, wv16, bk, bv, k16p, vt16, NB * TK, DM, DM, TK);

    // rope: q gets (1/sqrt(96))*log2(e) folded in
    const float qscale = 0.10206207261596577f * 1.4426950408889634f;
    rope_apply_k<<<(NB * NH * TQ * 48 + 255) / 256, 256, 0, stream>>>(
        q16, sinq, cosq, TQ, 96, qscale, NB * NH * TQ * 48);
    rope_apply_k<<<(NB * NH * TK * 48 + 255) / 256, 256, 0, stream>>>(
        k16p, sink, cosk, TK, 128, 1.0f, NB * NH * TK * 48);

    // attention
    attn_fwd<<<dim3(16, 16, 2), 256, 0, stream>>>(q16, k16p, vt16, at16);

    // output projection -> f32
    gemm16<1, 64><<<dim3(12, 32), 256, 0, stream>>>(
        at16, wo16, nullptr, bo, nullptr, out, nullptr, NB * TQ, DM, DM, TQ);
}

// Round 4
// 184.830 us; speedup vs baseline: 2.0838x; 1.1383x over previous
//
#include <hip/hip_runtime.h>
#include <math.h>

typedef _Float16 f16;
typedef __attribute__((ext_vector_type(4))) _Float16 f16x4;
typedef __attribute__((ext_vector_type(8))) _Float16 f16x8;
typedef __attribute__((ext_vector_type(4))) float f32x4;
typedef __attribute__((ext_vector_type(16))) float f32x16;

#define NB 2
#define NH 16
#define TQ 1024
#define TK 2048
#define DM 1536
#define HD 96
#define RH 48

__device__ __forceinline__ f32x4 mfma16(f16x8 a, f16x8 b, f32x4 c) {
    return __builtin_amdgcn_mfma_f32_16x16x32_f16(a, b, c, 0, 0, 0);
}

#define GLDS16(gptr, lptr) __builtin_amdgcn_global_load_lds( \
    (const __attribute__((address_space(1))) unsigned int*)(gptr), \
    (__attribute__((address_space(3))) unsigned int*)(lptr), 16, 0, 0)

// ---------------- conversions (fused launches) ----------------
__global__ void cvt_w4(const float4* __restrict__ W0, const float4* __restrict__ W1,
                       const float4* __restrict__ W2, const float4* __restrict__ W3,
                       f16x4* __restrict__ o0, f16x4* __restrict__ o1,
                       f16x4* __restrict__ o2, f16x4* __restrict__ o3, int n4) {
    int i = blockIdx.x * 256 + threadIdx.x;
    if (i >= n4) return;
    const float4* in = blockIdx.y == 0 ? W0 : blockIdx.y == 1 ? W1 : blockIdx.y == 2 ? W2 : W3;
    f16x4* out      = blockIdx.y == 0 ? o0 : blockIdx.y == 1 ? o1 : blockIdx.y == 2 ? o2 : o3;
    float4 v = in[i];
    f16x4 o;
    o[0] = (f16)v.x; o[1] = (f16)v.y; o[2] = (f16)v.z; o[3] = (f16)v.w;
    out[i] = o;
}

__global__ void cvt_xm(const float4* __restrict__ X, const float4* __restrict__ M,
                       f16x4* __restrict__ ox, f16x4* __restrict__ om, int nx4, int nm4) {
    int i = blockIdx.x * 256 + threadIdx.x;
    int n = blockIdx.y == 0 ? nx4 : nm4;
    if (i >= n) return;
    const float4* in = blockIdx.y == 0 ? X : M;
    f16x4* out = blockIdx.y == 0 ? ox : om;
    float4 v = in[i];
    f16x4 o;
    o[0] = (f16)v.x; o[1] = (f16)v.y; o[2] = (f16)v.z; o[3] = (f16)v.w;
    out[i] = o;
}

// ---------------- RoPE sin/cos tables: [B*T][48] ----------------
__global__ void rope_tab2(const float* __restrict__ cq, const float* __restrict__ cm,
                          float* __restrict__ sq, float* __restrict__ cqo,
                          float* __restrict__ sk, float* __restrict__ cko,
                          int nq, int nk) {
    int i = blockIdx.x * 256 + threadIdx.x;
    int n = blockIdx.y == 0 ? nq : nk;
    if (i >= n) return;
    const float* coords = blockIdx.y == 0 ? cq : cm;
    float* sinT = blockIdx.y == 0 ? sq : sk;
    float* cosT = blockIdx.y == 0 ? cqo : cko;
    int bt = i / 48, idx = i - bt * 48;
    int axis = idx >> 4, f = idx & 15;
    float inv = powf(10000.f, -(float)f * (1.f / 16.f));
    float ang = coords[bt * 3 + axis] * inv;
    sinT[i] = sinf(ang);
    cosT[i] = cosf(ang);
}

// ---------------- RoPE rotation in-place on [B,H,T,stride] f16 ----------------
__global__ void rope_apply_k(f16* __restrict__ qk, const float* __restrict__ sinT,
                             const float* __restrict__ cosT, int T, int stride,
                             float scale, int n) {
    int i = blockIdx.x * 256 + threadIdx.x;
    if (i >= n) return;
    int p = i % 48;
    int rest = i / 48;              // (b*NH + h)*T + t
    int t = rest % T;
    int b = rest / (NH * T);
    long base = (long)rest * stride;
    float x1 = (float)qk[base + p];
    float x2 = (float)qk[base + p + RH];
    int ti = (b * T + t) * 48 + p;
    float s = sinT[ti], c = cosT[ti];
    qk[base + p]      = (f16)((x1 * c - x2 * s) * scale);
    qk[base + p + RH] = (f16)((x2 * c + x1 * s) * scale);
}

// ---------------- GEMM v2: depth-2 prefetch pipeline ----------------
// C[m,n] = sum_k A[m,k]*W[n,k] + bias[n].  BN=128, BK=64, 512 threads (8 waves).
// 3 LDS buffers; iter t: wait vmcnt(LPS) -> barrier -> STAGE(t+2) -> compute(t).
// LDS tiles XOR-swizzled (seg ^= row&7, 16B segs) via pre-swizzled global source.
// MODE 1: f32 row-major (O-proj). MODE 4: fused K|V (bx<12 -> K padded [B,H,T,128],
// else V^T [B,H,96,TK]). MODE 5: f16 [B,H,T,96] (Q-proj).
template <int MODE, int BM>
__global__ __launch_bounds__(512, 2) void gemm3p(
    const f16* __restrict__ A, const f16* __restrict__ Wa, const f16* __restrict__ Wb,
    const float* __restrict__ ba, const float* __restrict__ bb,
    void* __restrict__ outa, void* __restrict__ outb,
    int M, int N, int K, int T) {
    constexpr int RA = BM / 64;          // A stage rounds (8KB each)
    constexpr int RB = 2;                // B stage rounds
    constexpr int LPS = RA + RB;         // loads per stage per thread
    constexpr int NW_M = BM / 64;        // waves along M (4 or 2)
    constexpr int NI = (NW_M == 4) ? 4 : 2;  // n-frags per wave
    constexpr int BUF = (BM + 128) * 64; // f16 per buffer

    __shared__ f16 Buf[3][BUF];

    const int tid = threadIdx.x;
    const int w = tid >> 6, lane = tid & 63;
    const int l15 = lane & 15, g = lane >> 4;
    int bx = blockIdx.x;
    const f16* W = Wa; const float* bias = ba; void* outp = outa;
    bool sel = false;
    if (MODE == 4 && bx >= 12) { sel = true; W = Wb; bias = bb; outp = outb; bx -= 12; }
    const int m0 = blockIdx.y * BM, n0 = bx * 128;
    const int wm = (w % NW_M) * 64;
    const int wn = (w / NW_M) * (NI * 16);

    // pre-swizzled per-lane global source offsets (f16 units)
    int asrc[RA], bsrc[RB];
#pragma unroll
    for (int r = 0; r < RA; r++) {
        int L = r * 8192 + w * 1024 + lane * 16;   // linear LDS byte offset in A tile
        int row = L >> 7, seg = (L >> 4) & 7;
        asrc[r] = row * K + ((seg ^ (row & 7)) << 3);
    }
#pragma unroll
    for (int r = 0; r < RB; r++) {
        int L = r * 8192 + w * 1024 + lane * 16;
        int row = L >> 7, seg = (L >> 4) & 7;
        bsrc[r] = row * K + ((seg ^ (row & 7)) << 3);
    }
    const f16* Ag = A + (long)m0 * K;
    const f16* Bg = W + (long)n0 * K;

#define STAGE3(bufi, kt) do { \
    _Pragma("unroll") for (int r_ = 0; r_ < RA; r_++) \
        GLDS16(Ag + asrc[r_] + (kt) * 64, &Buf[bufi][r_ * 4096 + w * 512]); \
    _Pragma("unroll") for (int r_ = 0; r_ < RB; r_++) \
        GLDS16(Bg + bsrc[r_] + (kt) * 64, &Buf[bufi][BM * 64 + r_ * 4096 + w * 512]); \
} while (0)

    f32x4 acc[4][NI] = {};
    const int NT = K >> 6;               // 24 K-tiles

    STAGE3(0, 0);
    STAGE3(1, 1);

    int cur = 0;
    for (int t = 0; t < NT; ++t) {
        if constexpr (LPS == 6) asm volatile("s_waitcnt vmcnt(6)" ::: "memory");
        else                    asm volatile("s_waitcnt vmcnt(4)" ::: "memory");
        __builtin_amdgcn_s_barrier();
        __builtin_amdgcn_sched_barrier(0);

        if (t + 2 < NT) {
            int nb = cur + 2; if (nb >= 3) nb -= 3;
            STAGE3(nb, t + 2);
        }
        __builtin_amdgcn_sched_barrier(0);

        const f16* ab = &Buf[cur][0];
        const f16* bbp = &Buf[cur][BM * 64];
        f16x8 af[4][2], bf[NI][2];
#pragma unroll
        for (int i = 0; i < 4; i++)
#pragma unroll
            for (int s = 0; s < 2; s++) {
                int row = wm + i * 16 + l15, seg = s * 4 + g;
                af[i][s] = *(const f16x8*)&ab[row * 64 + ((seg ^ (row & 7)) << 3)];
            }
#pragma unroll
        for (int j = 0; j < NI; j++)
#pragma unroll
            for (int s = 0; s < 2; s++) {
                int row = wn + j * 16 + l15, seg = s * 4 + g;
                bf[j][s] = *(const f16x8*)&bbp[row * 64 + ((seg ^ (row & 7)) << 3)];
            }
        __builtin_amdgcn_s_setprio(1);
#pragma unroll
        for (int s = 0; s < 2; s++)
#pragma unroll
            for (int i = 0; i < 4; i++)
#pragma unroll
                for (int j = 0; j < NI; j++)
                    acc[i][j] = mfma16(af[i][s], bf[j][s], acc[i][j]);
        __builtin_amdgcn_s_setprio(0);

        cur += 1; if (cur >= 3) cur -= 3;
    }
#undef STAGE3

    // ---- epilogue ----
#pragma unroll
    for (int i = 0; i < 4; i++) {
#pragma unroll
        for (int j = 0; j < NI; j++) {
            const int n = n0 + wn + j * 16 + l15;
            const int mb = m0 + wm + i * 16 + g * 4;
            if (MODE == 4 && sel) {            // V^T [B,H,96,TK]
                int bq = mb / T, t = mb - bq * T;
                int hh = n / HD, hd = n - hh * HD;
                f16x4 pk;
#pragma unroll
                for (int r = 0; r < 4; r++) pk[r] = (f16)(acc[i][j][r] + bias[n]);
                *(f16x4*)&((f16*)outp)[(((long)bq * NH + hh) * HD + hd) * TK + t] = pk;
            } else if (MODE == 4) {            // K padded [B,H,T,128]
#pragma unroll
                for (int r = 0; r < 4; r++) {
                    int m = mb + r;
                    int bq = m / T, t = m - bq * T;
                    int hh = n / HD, hd = n - hh * HD;
                    ((f16*)outp)[(((long)bq * NH + hh) * T + t) * 128 + hd] = (f16)(acc[i][j][r] + bias[n]);
                }
            } else if (MODE == 5) {            // Q [B,H,T,96]
#pragma unroll
                for (int r = 0; r < 4; r++) {
                    int m = mb + r;
                    int bq = m / T, t = m - bq * T;
                    int hh = n / HD, hd = n - hh * HD;
                    ((f16*)outp)[(((long)bq * NH + hh) * T + t) * 96 + hd] = (f16)(acc[i][j][r] + bias[n]);
                }
            } else {                           // f32 row-major
#pragma unroll
                for (int r = 0; r < 4; r++)
                    ((float*)outp)[(long)(mb + r) * N + n] = acc[i][j][r] + bias[n];
            }
        }
    }
}

// ---------------- Flash attention (round-3, unchanged) ----------------
__global__ __launch_bounds__(256, 2) void attn_fwd(
    const f16* __restrict__ Q, const f16* __restrict__ Kg,
    const f16* __restrict__ Vg, f16* __restrict__ O) {
    __shared__ f16 Kl[2][64 * 128];
    __shared__ f16 Vl[2][96 * 64];
    __shared__ f16 Pl[4][32 * 64];

    const int tid = threadIdx.x, w = tid >> 6, lane = tid & 63;
    const int q31 = lane & 31, hf = lane >> 5;
    const int half = w >> 1, u = w & 1;

    const int linear = blockIdx.x + (int)(gridDim.x * (blockIdx.y + gridDim.y * blockIdx.z));
    const int wid = (linear & 7) * 64 + (linear >> 3);
    const int qc = wid & 15, h = (wid >> 4) & 15, b = wid >> 8;

    const long kbase = (long)(b * NH + h) * TK * 128;
    const long vbase = (long)(b * NH + h) * HD * TK;
    const long qbase = (long)(b * NH + h) * TQ * 96;
    const int q0 = qc * 64 + u * 32;

    int ksrc[8], vsrc[6];
#pragma unroll
    for (int i = 0; i < 8; i++) {
        int L = (u * 8 + i) * 1024 + lane * 16;
        int r = L >> 8, s = (L >> 4) & 15;
        ksrc[i] = r * 128 + ((s ^ (r & 7)) << 3);
    }
#pragma unroll
    for (int i = 0; i < 6; i++) {
        int L = (u * 6 + i) * 1024 + lane * 16;
        int r = L >> 7, s = (L >> 4) & 7;
        vsrc[i] = r * TK + ((s ^ (r & 7)) << 3);
    }

    f16x8 qf[6];
#pragma unroll
    for (int s = 0; s < 6; s++)
        qf[s] = *(const f16x8*)&Q[qbase + (long)(q0 + q31) * 96 + hf * 8 + 16 * s];

    float mx = -3e38f, ls = 0.f;
    f32x16 acc[3] = {};

#define STAGE(c_) do { \
    const f16* kp_ = Kg + kbase + (long)(half * 16 + (c_)) * (64 * 128); \
    _Pragma("unroll") for (int i_ = 0; i_ < 8; i_++) \
        GLDS16(kp_ + ksrc[i_], &Kl[half][(u * 8 + i_) * 512]); \
    const f16* vp_ = Vg + vbase + (half * 16 + (c_)) * 64; \
    _Pragma("unroll") for (int i_ = 0; i_ < 6; i_++) \
        GLDS16(vp_ + vsrc[i_], &Vl[half][(u * 6 + i_) * 512]); \
} while (0)

    STAGE(0);

    for (int c = 0; c < 16; ++c) {
        __syncthreads();

        f32x16 st[2] = {};
#pragma unroll
        for (int kt = 0; kt < 2; kt++)
#pragma unroll
            for (int s = 0; s < 6; s++) {
                f16x8 kf = *(const f16x8*)&Kl[half][(kt * 32 + q31) * 128 +
                                                    (((hf + 2 * s) ^ (q31 & 7)) << 3)];
                st[kt] = __builtin_amdgcn_mfma_f32_32x32x16_f16(kf, qf[s], st[kt], 0, 0, 0);
            }

        float t16[16];
#pragma unroll
        for (int r = 0; r < 16; r++) t16[r] = fmaxf(st[0][r], st[1][r]);
#pragma unroll
        for (int o = 8; o >= 1; o >>= 1)
#pragma unroll
            for (int r = 0; r < o; r++) t16[r] = fmaxf(t16[r], t16[r + o]);
        float cm = fmaxf(t16[0], __shfl_xor(t16[0], 32));
        float mn = fmaxf(mx, cm);
        float corr = exp2f(mx - mn);
        mx = mn;
#pragma unroll
        for (int kt = 0; kt < 2; kt++)
#pragma unroll
            for (int r = 0; r < 16; r++) st[kt][r] = exp2f(st[kt][r] - mn);
        float s16[16];
#pragma unroll
        for (int r = 0; r < 16; r++) s16[r] = st[0][r] + st[1][r];
#pragma unroll
        for (int o = 8; o >= 1; o >>= 1)
#pragma unroll
            for (int r = 0; r < o; r++) s16[r] += s16[r + o];
        ls = ls * corr + s16[0];
#pragma unroll
        for (int dt = 0; dt < 3; dt++)
#pragma unroll
            for (int r = 0; r < 16; r++) acc[dt][r] *= corr;

#pragma unroll
        for (int kt = 0; kt < 2; kt++)
#pragma unroll
            for (int jq = 0; jq < 4; jq++) {
                f16x4 pk;
#pragma unroll
                for (int e = 0; e < 4; e++) pk[e] = (f16)st[kt][jq * 4 + e];
                int seg = kt * 4 + jq;
                *(f16x4*)&Pl[w][q31 * 64 + ((seg ^ (q31 & 7)) << 3) + hf * 4] = pk;
            }

#pragma unroll
        for (int ks = 0; ks < 4; ks++) {
            f16x8 pf = *(const f16x8*)&Pl[w][q31 * 64 + (((hf + 2 * ks) ^ (q31 & 7)) << 3)];
#pragma unroll
            for (int dt = 0; dt < 3; dt++) {
                f16x8 vf = *(const f16x8*)&Vl[half][(dt * 32 + q31) * 64 +
                                                    (((hf + 2 * ks) ^ (q31 & 7)) << 3)];
                acc[dt] = __builtin_amdgcn_mfma_f32_32x32x16_f16(vf, pf, acc[dt], 0, 0, 0);
            }
        }

        __syncthreads();
        if (c < 15) STAGE(c + 1);
    }

    ls += __shfl_xor(ls, 32);
    float* dump = (float*)&Kl[0][0] + u * (64 * 52);
    __syncthreads();
    if (half == 1) {
        float* dl = dump + lane * 52;
        dl[0] = mx; dl[1] = ls;
#pragma unroll
        for (int dt = 0; dt < 3; dt++)
#pragma unroll
            for (int r = 0; r < 16; r++) dl[2 + dt * 16 + r] = acc[dt][r];
    }
    __syncthreads();
    if (half == 0) {
        const float* dl = dump + lane * 52;
        float mb = dl[0], lsb = dl[1];
        float mf = fmaxf(mx, mb);
        float ca = exp2f(mx - mf), cb = exp2f(mb - mf);
        float inv = 1.f / (ls * ca + lsb * cb);
        const long orow = (long)(b * TQ + q0 + q31) * DM + h * 96;
#pragma unroll
        for (int dt = 0; dt < 3; dt++)
#pragma unroll
            for (int jq = 0; jq < 4; jq++) {
                f16x4 ov;
#pragma unroll
                for (int e = 0; e < 4; e++) {
                    int r = jq * 4 + e;
                    ov[e] = (f16)((acc[dt][r] * ca + dl[2 + dt * 16 + r] * cb) * inv);
                }
                *(f16x4*)&O[orow + dt * 32 + jq * 8 + hf * 4] = ov;
            }
    }
}

// ---------------- host ----------------
extern "C" void kernel_launch(void* const* d_in, const int* in_sizes, int n_in,
                              void* d_out, int out_size, void* d_ws, size_t ws_size,
                              hipStream_t stream) {
    const float* x   = (const float*)d_in[0];
    const float* mem = (const float*)d_in[1];
    const float* qc  = (const float*)d_in[2];
    const float* mc  = (const float*)d_in[3];
    const float* Wq  = (const float*)d_in[4];
    const float* bq  = (const float*)d_in[5];
    const float* Wk  = (const float*)d_in[6];
    const float* bk  = (const float*)d_in[7];
    const float* Wv  = (const float*)d_in[8];
    const float* bv  = (const float*)d_in[9];
    const float* Wo  = (const float*)d_in[10];
    const float* bo  = (const float*)d_in[11];
    float* out = (float*)d_out;

    const long nx  = (long)NB * TQ * DM;
    const long nm  = (long)NB * TK * DM;
    const long nw  = (long)DM * DM;
    const long nq  = (long)NB * NH * TQ * 96;
    const long nkp = (long)NB * NH * TK * 128;
    const long nvt = (long)NB * NH * HD * TK;

    char* ws = (char*)d_ws;
    size_t off = 0;
    auto alloc = [&](size_t bytes) { size_t o = off; off = (off + bytes + 255) & ~(size_t)255; return o; };
    f16* x16   = (f16*)(ws + alloc(nx * 2));     // reused as at16 after Q-proj
    f16* mem16 = (f16*)(ws + alloc(nm * 2));
    f16* wq16  = (f16*)(ws + alloc(nw * 2));
    f16* wk16  = (f16*)(ws + alloc(nw * 2));
    f16* wv16  = (f16*)(ws + alloc(nw * 2));
    f16* wo16  = (f16*)(ws + alloc(nw * 2));
    f16* q16   = (f16*)(ws + alloc(nq * 2));
    f16* k16p  = (f16*)(ws + alloc(nkp * 2));
    f16* vt16  = (f16*)(ws + alloc(nvt * 2));
    float* sinq = (float*)(ws + alloc((size_t)NB * TQ * 48 * 4));
    float* cosq = (float*)(ws + alloc((size_t)NB * TQ * 48 * 4));
    float* sink = (float*)(ws + alloc((size_t)NB * TK * 48 * 4));
    float* cosk = (float*)(ws + alloc((size_t)NB * TK * 48 * 4));
    f16* at16 = x16;

    cvt_w4<<<dim3((int)(nw / 4 / 256), 4), 256, 0, stream>>>(
        (const float4*)Wq, (const float4*)Wk, (const float4*)Wv, (const float4*)Wo,
        (f16x4*)wq16, (f16x4*)wk16, (f16x4*)wv16, (f16x4*)wo16, (int)(nw / 4));
    cvt_xm<<<dim3((int)(nm / 4 / 256), 2), 256, 0, stream>>>(
        (const float4*)x, (const float4*)mem, (f16x4*)x16, (f16x4*)mem16,
        (int)(nx / 4), (int)(nm / 4));

    rope_tab2<<<dim3((NB * TK * 48 + 255) / 256, 2), 256, 0, stream>>>(
        qc, mc, sinq, cosq, sink, cosk, NB * TQ * 48, NB * TK * 48);

    // projections: Q (128x128 tiles, 192 blocks), fused K|V (256x128 tiles, 384 blocks)
    gemm3p<5, 128><<<dim3(12, 16), 512, 0, stream>>>(
        x16, wq16, nullptr, bq, nullptr, q16, nullptr, NB * TQ, DM, DM, TQ);
    gemm3p<4, 256><<<dim3(24, 16), 512, 0, stream>>>(
        mem16, wk16, wv16, bk, bv, k16p, vt16, NB * TK, DM, DM, TK);

    const float qscale = 0.10206207261596577f * 1.4426950408889634f;  // 1/sqrt(96)*log2(e)
    rope_apply_k<<<(NB * NH * TQ * 48 + 255) / 256, 256, 0, stream>>>(
        q16, sinq, cosq, TQ, 96, qscale, NB * NH * TQ * 48);
    rope_apply_k<<<(NB * NH * TK * 48 + 255) / 256, 256, 0, stream>>>(
        k16p, sink, cosk, TK, 128, 1.0f, NB * NH * TK * 48);

    attn_fwd<<<dim3(16, 16, 2), 256, 0, stream>>>(q16, k16p, vt16, at16);

    gemm3p<1, 128><<<dim3(12, 16), 512, 0, stream>>>(
        at16, wo16, nullptr, bo, nullptr, out, nullptr, NB * TQ, DM, DM, TQ);
}